// Round 12
// baseline (215.655 us; speedup 1.0000x reference)
//
#include <hip/hip_runtime.h>
#include <array>

namespace {

constexpr int NPAIRS = 40000;
constexpr long NF = (long)NPAIRS * 128;  // elements per (l,m) plane

// ---------------------------------------------------------------------------
// Compile-time enumeration of nonzero CG terms (symmetrized):
// out[o] += (cg[o,a,b]+cg[o,b,a]) * x[a] * y[b]
// ---------------------------------------------------------------------------
struct Term {
  int o, a, b;
};

constexpr int count_terms() {
  int idx = 0;
  for (int o = 0; o < 15; ++o) {
    const int l3 = o / 5, m3 = o % 5 - 2;
    if (m3 < -l3 || m3 > l3) continue;
    for (int l1 = 0; l1 < 3; ++l1)
      for (int l2 = 0; l2 < 3; ++l2) {
        const int ld = l1 > l2 ? l1 - l2 : l2 - l1;
        if (l3 < ld || l3 > l1 + l2) continue;
        const int mlo = (-l1 > m3 - l2) ? -l1 : m3 - l2;
        const int mhi = (l1 < m3 + l2) ? l1 : m3 + l2;
        for (int m1 = mlo; m1 <= mhi; ++m1) ++idx;
      }
  }
  return idx;
}
constexpr int NTERMS = count_terms();
static_assert(NTERMS == 117, "term count");

constexpr std::array<Term, NTERMS> make_terms() {
  std::array<Term, NTERMS> t{};
  int idx = 0;
  for (int o = 0; o < 15; ++o) {
    const int l3 = o / 5, m3 = o % 5 - 2;
    if (m3 < -l3 || m3 > l3) continue;
    for (int l1 = 0; l1 < 3; ++l1)
      for (int l2 = 0; l2 < 3; ++l2) {
        const int ld = l1 > l2 ? l1 - l2 : l2 - l1;
        if (l3 < ld || l3 > l1 + l2) continue;
        const int mlo = (-l1 > m3 - l2) ? -l1 : m3 - l2;
        const int mhi = (l1 < m3 + l2) ? l1 : m3 + l2;
        for (int m1 = mlo; m1 <= mhi; ++m1) {
          t[idx].o = o;
          t[idx].a = l1 * 5 + m1 + 2;
          t[idx].b = l2 * 5 + (m3 - m1) + 2;
          ++idx;
        }
      }
  }
  return t;
}
constexpr auto TERMS = make_terms();

// Plane -> dense index for the 9 valid (l,m) slots; -1 for the 6 zero slots.
constexpr std::array<int, 15> make_acc_idx() {
  std::array<int, 15> m{};
  for (int o = 0; o < 15; ++o) m[o] = -1;
  int q = 0;
  for (int o = 0; o < 15; ++o) {
    const int l3 = o / 5, m3 = o % 5 - 2;
    if (m3 >= -l3 && m3 <= l3) m[o] = q++;
  }
  return m;
}
constexpr auto ACC_IDX = make_acc_idx();

constexpr std::array<int, 9> make_used() {
  std::array<int, 9> u{};
  int q = 0;
  for (int o = 0; o < 15; ++o)
    if (ACC_IDX[o] >= 0) u[q++] = o;
  return u;
}
constexpr auto USED = make_used();  // {2,6,7,8,10,11,12,13,14}

// The 6 identically-zero output planes.
__constant__ constexpr int ZPLANES[6] = {0, 1, 3, 4, 5, 9};

// ---------------------------------------------------------------------------
// Kernel A: s[n,f] = (w1 h)(w2 h) -> s_out; also zero-fills the zero output
// planes (memory pipe idle during the GEMM). Proven R7 config.
// ---------------------------------------------------------------------------
__global__ __launch_bounds__(256, 4) void s_kernel(const float* __restrict__ g,
                                                   const float* __restrict__ w1,
                                                   const float* __restrict__ w2,
                                                   float* __restrict__ s_out,
                                                   float* __restrict__ out,
                                                   int zstart) {
  __shared__ float ht[128][32];
  __shared__ float wt1[16][132];
  __shared__ float wt2[16][132];

  const int tid = threadIdx.x;
  const int blk = blockIdx.x;

  if (tid < 32) {
    const float gv = g[blk * 32 + tid];
    float hkm1 = 0.75112554446494248286f * expf(-0.5f * gv * gv);
    float hk = 1.41421356237309504880f * gv * hkm1;
    ht[0][tid] = hkm1;
    ht[1][tid] = hk;
#pragma unroll 1
    for (int k = 1; k <= 126; ++k) {
      const float kf = (float)k;
      const float hkp1 =
          sqrtf(2.0f / (kf + 1.0f)) * gv * hk - sqrtf(kf / (kf + 1.0f)) * hkm1;
      ht[k + 1][tid] = hkp1;
      hkm1 = hk;
      hk = hkp1;
    }
  }

  // Zero-fill the zero output planes (overlaps the GEMM's compute phases).
  {
    const long idx = (long)blk * 256 + tid;
    const float4 z = make_float4(0.f, 0.f, 0.f, 0.f);
    for (int zp = zstart; zp < 6; ++zp) {
      float* base = out + (long)ZPLANES[zp] * NF;
#pragma unroll
      for (int r = 0; r < 4; ++r)
        *(float4*)(base + (r * 320000 + idx) * 4) = z;
    }
  }

  const int fg = tid & 31;
  const int ng = tid >> 5;

  float acc1[4][4];
  float acc2[4][4];
#pragma unroll
  for (int i = 0; i < 4; ++i)
#pragma unroll
    for (int j = 0; j < 4; ++j) {
      acc1[i][j] = 0.f;
      acc2[i][j] = 0.f;
    }

  for (int kc = 0; kc < 8; ++kc) {
#pragma unroll
    for (int it = 0; it < 2; ++it) {
      const int lin = tid + it * 256;
      const int f = lin >> 2;
      const int kq = lin & 3;
      const float4 v1 = *(const float4*)(w1 + f * 128 + kc * 16 + kq * 4);
      const float4 v2 = *(const float4*)(w2 + f * 128 + kc * 16 + kq * 4);
      wt1[kq * 4 + 0][f] = v1.x;
      wt1[kq * 4 + 1][f] = v1.y;
      wt1[kq * 4 + 2][f] = v1.z;
      wt1[kq * 4 + 3][f] = v1.w;
      wt2[kq * 4 + 0][f] = v2.x;
      wt2[kq * 4 + 1][f] = v2.y;
      wt2[kq * 4 + 2][f] = v2.z;
      wt2[kq * 4 + 3][f] = v2.w;
    }
    __syncthreads();

#pragma unroll
    for (int kk = 0; kk < 16; ++kk) {
      const float4 wv1 = *(const float4*)&wt1[kk][fg * 4];
      const float4 wv2 = *(const float4*)&wt2[kk][fg * 4];
      const float4 ha = *(const float4*)&ht[kc * 16 + kk][ng * 4];
      const float hv[4] = {ha.x, ha.y, ha.z, ha.w};
#pragma unroll
      for (int i = 0; i < 4; ++i) {
        acc1[i][0] = fmaf(hv[i], wv1.x, acc1[i][0]);
        acc1[i][1] = fmaf(hv[i], wv1.y, acc1[i][1]);
        acc1[i][2] = fmaf(hv[i], wv1.z, acc1[i][2]);
        acc1[i][3] = fmaf(hv[i], wv1.w, acc1[i][3]);
        acc2[i][0] = fmaf(hv[i], wv2.x, acc2[i][0]);
        acc2[i][1] = fmaf(hv[i], wv2.y, acc2[i][1]);
        acc2[i][2] = fmaf(hv[i], wv2.z, acc2[i][2]);
        acc2[i][3] = fmaf(hv[i], wv2.w, acc2[i][3]);
      }
    }
    __syncthreads();
  }

#pragma unroll
  for (int i = 0; i < 4; ++i) {
    const long n = (long)blk * 32 + ng * 4 + i;
    float4 sv;
    sv.x = acc1[i][0] * acc2[i][0];
    sv.y = acc1[i][1] * acc2[i][1];
    sv.z = acc1[i][2] * acc2[i][2];
    sv.w = acc1[i][3] * acc2[i][3];
    *(float4*)(s_out + n * 128 + fg * 4) = sv;
  }
}

// ---------------------------------------------------------------------------
// Kernel B: R11's proven float2 shape, plane-blocked: each block owns a
// 4096-float window per plane and walks it in 8 sequential 512-float steps,
// so every one of the 27 streams advances in 16 KB contiguous runs per block
// (DRAM row-hit batching) instead of isolated 2 KB touches. No scheduling
// attributes; compiler-managed batching at VGPR ~90.
// ---------------------------------------------------------------------------
__global__ __launch_bounds__(256) void tp_kernel(const float* __restrict__ x,
                                                 const float* __restrict__ y,
                                                 const float* __restrict__ cg,
                                                 const float* __restrict__ s_in,
                                                 float* __restrict__ out,
                                                 int zero_p0) {
  __shared__ float d2s[NTERMS];
  const int tid = threadIdx.x;
  if (tid < NTERMS) {
    const Term tm = TERMS[tid];
    d2s[tid] = cg[(tm.o * 15 + tm.a) * 15 + tm.b] + cg[(tm.o * 15 + tm.b) * 15 + tm.a];
  }
  __syncthreads();

  const long wbase = (long)blockIdx.x * 4096 + tid * 2;  // window base for this thread

#pragma unroll 1
  for (int j = 0; j < 8; ++j) {
    const long off = wbase + j * 512;

    float2 xv[9], yv[9];
#pragma unroll
    for (int q = 0; q < 9; ++q) xv[q] = *(const float2*)(x + (long)USED[q] * NF + off);
#pragma unroll
    for (int q = 0; q < 9; ++q) yv[q] = *(const float2*)(y + (long)USED[q] * NF + off);
    const float2 sv = *(const float2*)(s_in + off);

    float accx[9], accy[9];
#pragma unroll
    for (int q = 0; q < 9; ++q) {
      accx[q] = 0.f;
      accy[q] = 0.f;
    }

#pragma unroll
    for (int t = 0; t < NTERMS; ++t) {
      const int qo = ACC_IDX[TERMS[t].o];
      const int qa = ACC_IDX[TERMS[t].a];
      const int qb = ACC_IDX[TERMS[t].b];
      const float c = d2s[t];
      accx[qo] = fmaf(c, xv[qa].x * yv[qb].x, accx[qo]);
      accy[qo] = fmaf(c, xv[qa].y * yv[qb].y, accy[qo]);
    }

    if (zero_p0) {
      *(float2*)(out + off) = make_float2(0.f, 0.f);
    }

#pragma unroll
    for (int q = 0; q < 9; ++q) {
      float2 r;
      r.x = accx[q] * sv.x;
      r.y = accy[q] * sv.y;
      *(float2*)(out + (long)USED[q] * NF + off) = r;
    }
  }
}

}  // namespace

extern "C" void kernel_launch(void* const* d_in, const int* in_sizes, int n_in,
                              void* d_out, int out_size, void* d_ws, size_t ws_size,
                              hipStream_t stream) {
  const float* x = (const float*)d_in[0];
  const float* y = (const float*)d_in[1];
  const float* g = (const float*)d_in[2];
  const float* w1 = (const float*)d_in[3];
  const float* w2 = (const float*)d_in[4];
  const float* cg = (const float*)d_in[5];
  float* out = (float*)d_out;

  const size_t s_bytes = (size_t)NF * sizeof(float);  // 20.48 MB
  const bool use_ws = ws_size >= s_bytes;
  float* s_buf = use_ws ? (float*)d_ws : out;  // fallback: plane 0 of out

  // Pass 1: s + zero-fill of the zero output planes.
  s_kernel<<<1250, 256, 0, stream>>>(g, w1, w2, s_buf, out, use_ws ? 0 : 1);
  // Pass 2: plane-blocked contraction; writes the 9 nonzero planes.
  tp_kernel<<<1250, 256, 0, stream>>>(x, y, cg, s_buf, out, use_ws ? 0 : 1);
}

// Round 13
// 203.452 us; speedup vs baseline: 1.0600x; 1.0600x over previous
//
#include <hip/hip_runtime.h>
#include <array>

namespace {

constexpr int NPAIRS = 40000;
constexpr long NF = (long)NPAIRS * 128;  // elements per (l,m) plane

// ---------------------------------------------------------------------------
// Compile-time enumeration of nonzero CG terms (symmetrized):
// out[o] += (cg[o,a,b]+cg[o,b,a]) * x[a] * y[b]
// ---------------------------------------------------------------------------
struct Term {
  int o, a, b;
};

constexpr int count_terms() {
  int idx = 0;
  for (int o = 0; o < 15; ++o) {
    const int l3 = o / 5, m3 = o % 5 - 2;
    if (m3 < -l3 || m3 > l3) continue;
    for (int l1 = 0; l1 < 3; ++l1)
      for (int l2 = 0; l2 < 3; ++l2) {
        const int ld = l1 > l2 ? l1 - l2 : l2 - l1;
        if (l3 < ld || l3 > l1 + l2) continue;
        const int mlo = (-l1 > m3 - l2) ? -l1 : m3 - l2;
        const int mhi = (l1 < m3 + l2) ? l1 : m3 + l2;
        for (int m1 = mlo; m1 <= mhi; ++m1) ++idx;
      }
  }
  return idx;
}
constexpr int NTERMS = count_terms();
static_assert(NTERMS == 117, "term count");

constexpr std::array<Term, NTERMS> make_terms() {
  std::array<Term, NTERMS> t{};
  int idx = 0;
  for (int o = 0; o < 15; ++o) {
    const int l3 = o / 5, m3 = o % 5 - 2;
    if (m3 < -l3 || m3 > l3) continue;
    for (int l1 = 0; l1 < 3; ++l1)
      for (int l2 = 0; l2 < 3; ++l2) {
        const int ld = l1 > l2 ? l1 - l2 : l2 - l1;
        if (l3 < ld || l3 > l1 + l2) continue;
        const int mlo = (-l1 > m3 - l2) ? -l1 : m3 - l2;
        const int mhi = (l1 < m3 + l2) ? l1 : m3 + l2;
        for (int m1 = mlo; m1 <= mhi; ++m1) {
          t[idx].o = o;
          t[idx].a = l1 * 5 + m1 + 2;
          t[idx].b = l2 * 5 + (m3 - m1) + 2;
          ++idx;
        }
      }
  }
  return t;
}
constexpr auto TERMS = make_terms();

// Plane -> dense index for the 9 valid (l,m) slots; -1 for the 6 zero slots.
constexpr std::array<int, 15> make_acc_idx() {
  std::array<int, 15> m{};
  for (int o = 0; o < 15; ++o) m[o] = -1;
  int q = 0;
  for (int o = 0; o < 15; ++o) {
    const int l3 = o / 5, m3 = o % 5 - 2;
    if (m3 >= -l3 && m3 <= l3) m[o] = q++;
  }
  return m;
}
constexpr auto ACC_IDX = make_acc_idx();

constexpr std::array<int, 9> make_used() {
  std::array<int, 9> u{};
  int q = 0;
  for (int o = 0; o < 15; ++o)
    if (ACC_IDX[o] >= 0) u[q++] = o;
  return u;
}
constexpr auto USED = make_used();  // {2,6,7,8,10,11,12,13,14}

// The 6 identically-zero output planes.
__constant__ constexpr int ZPLANES[6] = {0, 1, 3, 4, 5, 9};

// ---------------------------------------------------------------------------
// Kernel A: s[n,f] = (w1 h)(w2 h) -> s_out; also zero-fills the zero output
// planes (memory pipe idle during the GEMM). Proven R7/R11 config.
// ---------------------------------------------------------------------------
__global__ __launch_bounds__(256, 4) void s_kernel(const float* __restrict__ g,
                                                   const float* __restrict__ w1,
                                                   const float* __restrict__ w2,
                                                   float* __restrict__ s_out,
                                                   float* __restrict__ out,
                                                   int zstart) {
  __shared__ float ht[128][32];
  __shared__ float wt1[16][132];
  __shared__ float wt2[16][132];

  const int tid = threadIdx.x;
  const int blk = blockIdx.x;

  if (tid < 32) {
    const float gv = g[blk * 32 + tid];
    float hkm1 = 0.75112554446494248286f * expf(-0.5f * gv * gv);
    float hk = 1.41421356237309504880f * gv * hkm1;
    ht[0][tid] = hkm1;
    ht[1][tid] = hk;
#pragma unroll 1
    for (int k = 1; k <= 126; ++k) {
      const float kf = (float)k;
      const float hkp1 =
          sqrtf(2.0f / (kf + 1.0f)) * gv * hk - sqrtf(kf / (kf + 1.0f)) * hkm1;
      ht[k + 1][tid] = hkp1;
      hkm1 = hk;
      hk = hkp1;
    }
  }

  // Zero-fill the zero output planes (overlaps the GEMM's compute phases).
  {
    const long idx = (long)blk * 256 + tid;
    const float4 z = make_float4(0.f, 0.f, 0.f, 0.f);
    for (int zp = zstart; zp < 6; ++zp) {
      float* base = out + (long)ZPLANES[zp] * NF;
#pragma unroll
      for (int r = 0; r < 4; ++r)
        *(float4*)(base + (r * 320000 + idx) * 4) = z;
    }
  }

  const int fg = tid & 31;
  const int ng = tid >> 5;

  float acc1[4][4];
  float acc2[4][4];
#pragma unroll
  for (int i = 0; i < 4; ++i)
#pragma unroll
    for (int j = 0; j < 4; ++j) {
      acc1[i][j] = 0.f;
      acc2[i][j] = 0.f;
    }

  for (int kc = 0; kc < 8; ++kc) {
#pragma unroll
    for (int it = 0; it < 2; ++it) {
      const int lin = tid + it * 256;
      const int f = lin >> 2;
      const int kq = lin & 3;
      const float4 v1 = *(const float4*)(w1 + f * 128 + kc * 16 + kq * 4);
      const float4 v2 = *(const float4*)(w2 + f * 128 + kc * 16 + kq * 4);
      wt1[kq * 4 + 0][f] = v1.x;
      wt1[kq * 4 + 1][f] = v1.y;
      wt1[kq * 4 + 2][f] = v1.z;
      wt1[kq * 4 + 3][f] = v1.w;
      wt2[kq * 4 + 0][f] = v2.x;
      wt2[kq * 4 + 1][f] = v2.y;
      wt2[kq * 4 + 2][f] = v2.z;
      wt2[kq * 4 + 3][f] = v2.w;
    }
    __syncthreads();

#pragma unroll
    for (int kk = 0; kk < 16; ++kk) {
      const float4 wv1 = *(const float4*)&wt1[kk][fg * 4];
      const float4 wv2 = *(const float4*)&wt2[kk][fg * 4];
      const float4 ha = *(const float4*)&ht[kc * 16 + kk][ng * 4];
      const float hv[4] = {ha.x, ha.y, ha.z, ha.w};
#pragma unroll
      for (int i = 0; i < 4; ++i) {
        acc1[i][0] = fmaf(hv[i], wv1.x, acc1[i][0]);
        acc1[i][1] = fmaf(hv[i], wv1.y, acc1[i][1]);
        acc1[i][2] = fmaf(hv[i], wv1.z, acc1[i][2]);
        acc1[i][3] = fmaf(hv[i], wv1.w, acc1[i][3]);
        acc2[i][0] = fmaf(hv[i], wv2.x, acc2[i][0]);
        acc2[i][1] = fmaf(hv[i], wv2.y, acc2[i][1]);
        acc2[i][2] = fmaf(hv[i], wv2.z, acc2[i][2]);
        acc2[i][3] = fmaf(hv[i], wv2.w, acc2[i][3]);
      }
    }
    __syncthreads();
  }

#pragma unroll
  for (int i = 0; i < 4; ++i) {
    const long n = (long)blk * 32 + ng * 4 + i;
    float4 sv;
    sv.x = acc1[i][0] * acc2[i][0];
    sv.y = acc1[i][1] * acc2[i][1];
    sv.z = acc1[i][2] * acc2[i][2];
    sv.w = acc1[i][3] * acc2[i][3];
    *(float4*)(s_out + n * 128 + fg * 4) = sv;
  }
}

// ---------------------------------------------------------------------------
// Kernel B: best-measured configuration (R11, 204 us total): float2/thread,
// vanilla scheduling, high occupancy, 9-plane reads, 9-plane writes.
// ---------------------------------------------------------------------------
__global__ __launch_bounds__(256) void tp_kernel(const float* __restrict__ x,
                                                 const float* __restrict__ y,
                                                 const float* __restrict__ cg,
                                                 const float* __restrict__ s_in,
                                                 float* __restrict__ out,
                                                 int zero_p0) {
  __shared__ float d2s[NTERMS];
  const int tid = threadIdx.x;
  if (tid < NTERMS) {
    const Term tm = TERMS[tid];
    d2s[tid] = cg[(tm.o * 15 + tm.a) * 15 + tm.b] + cg[(tm.o * 15 + tm.b) * 15 + tm.a];
  }
  __syncthreads();

  const long off = ((long)blockIdx.x * 256 + tid) * 2;  // float2 element offset

  float2 xv[9], yv[9];
#pragma unroll
  for (int q = 0; q < 9; ++q) xv[q] = *(const float2*)(x + (long)USED[q] * NF + off);
#pragma unroll
  for (int q = 0; q < 9; ++q) yv[q] = *(const float2*)(y + (long)USED[q] * NF + off);
  const float2 sv = *(const float2*)(s_in + off);

  float accx[9], accy[9];
#pragma unroll
  for (int q = 0; q < 9; ++q) {
    accx[q] = 0.f;
    accy[q] = 0.f;
  }

#pragma unroll
  for (int t = 0; t < NTERMS; ++t) {
    const int qo = ACC_IDX[TERMS[t].o];
    const int qa = ACC_IDX[TERMS[t].a];
    const int qb = ACC_IDX[TERMS[t].b];
    const float c = d2s[t];
    accx[qo] = fmaf(c, xv[qa].x * yv[qb].x, accx[qo]);
    accy[qo] = fmaf(c, xv[qa].y * yv[qb].y, accy[qo]);
  }

  // If s was staged in plane 0 of out, zero it now (sv already read).
  if (zero_p0) {
    *(float2*)(out + off) = make_float2(0.f, 0.f);
  }

#pragma unroll
  for (int q = 0; q < 9; ++q) {
    float2 r;
    r.x = accx[q] * sv.x;
    r.y = accy[q] * sv.y;
    *(float2*)(out + (long)USED[q] * NF + off) = r;
  }
}

}  // namespace

extern "C" void kernel_launch(void* const* d_in, const int* in_sizes, int n_in,
                              void* d_out, int out_size, void* d_ws, size_t ws_size,
                              hipStream_t stream) {
  const float* x = (const float*)d_in[0];
  const float* y = (const float*)d_in[1];
  const float* g = (const float*)d_in[2];
  const float* w1 = (const float*)d_in[3];
  const float* w2 = (const float*)d_in[4];
  const float* cg = (const float*)d_in[5];
  float* out = (float*)d_out;

  const size_t s_bytes = (size_t)NF * sizeof(float);  // 20.48 MB
  const bool use_ws = ws_size >= s_bytes;
  float* s_buf = use_ws ? (float*)d_ws : out;  // fallback: plane 0 of out

  // Pass 1: s + zero-fill of the zero output planes.
  s_kernel<<<1250, 256, 0, stream>>>(g, w1, w2, s_buf, out, use_ws ? 0 : 1);
  // Pass 2: contraction (float2/thread, 10000 blocks); 9 nonzero planes.
  tp_kernel<<<10000, 256, 0, stream>>>(x, y, cg, s_buf, out, use_ws ? 0 : 1);
}